// Round 1
// baseline (14831.828 us; speedup 1.0000x reference)
//
#include <hip/hip_runtime.h>

#define Bz   32
#define Sz   64
#define Tdec 63
#define Ez   256
#define Hz   512
#define H3z  1536
#define Vz   32000

typedef __attribute__((ext_vector_type(4))) float floatx4;
typedef __attribute__((ext_vector_type(8))) short shortx8;

__device__ __forceinline__ unsigned short f2bf(float f) {
  unsigned x = __float_as_uint(f);
  unsigned r = (x + 0x7fffu + ((x >> 16) & 1u)) >> 16;
  return (unsigned short)r;
}

// ---------------- generic transpose: out[c][r] = in[r][c0+c] ----------------
__global__ __launch_bounds__(256)
void k_transpose(const float* __restrict__ in, int R, int Ctot, int c0,
                 float* __restrict__ out) {
  __shared__ float tile[32][33];
  int ct = blockIdx.x * 32;
  int rt = blockIdx.y * 32;
  int lx = threadIdx.x & 31, ly = threadIdx.x >> 5;  // 32 x 8
#pragma unroll
  for (int i = 0; i < 32; i += 8)
    tile[ly + i][lx] = in[(long)(rt + ly + i) * Ctot + c0 + ct + lx];
  __syncthreads();
#pragma unroll
  for (int i = 0; i < 32; i += 8)
    out[(long)(ct + ly + i) * R + rt + lx] = tile[lx][ly + i];
}

// -------- embed + input-GEMM: G[r][j] = bias[j] + sum_k emb[tok_r][k]*WT[k][j]
// tok_r = toks[(r%32)*64 + r/32]   (row r = t*32 + b)
__global__ __launch_bounds__(256)
void k_embed_gi(const int* __restrict__ toks, const float* __restrict__ emb,
                const float* __restrict__ WT, const float* __restrict__ bias,
                float* __restrict__ G) {
  __shared__ float se[16][Ez];
  int jg = blockIdx.x % 24;
  int rg = blockIdx.x / 24;
  int r0 = rg * 16;
  int tid = threadIdx.x;
  for (int c = tid; c < 16 * Ez; c += 256) {
    int rl = c >> 8;
    int k = c & 255;
    int r = r0 + rl;
    int tok = toks[(r & 31) * 64 + (r >> 5)];
    se[rl][k] = emb[(long)tok * Ez + k];
  }
  __syncthreads();
  int jj = tid & 63, rq = tid >> 6;
  int j = jg * 64 + jj;
  float a0 = 0.f, a1 = 0.f, a2 = 0.f, a3 = 0.f;
#pragma unroll 4
  for (int k = 0; k < Ez; ++k) {
    float w = WT[(long)k * H3z + j];
    a0 = fmaf(se[rq * 4 + 0][k], w, a0);
    a1 = fmaf(se[rq * 4 + 1][k], w, a1);
    a2 = fmaf(se[rq * 4 + 2][k], w, a2);
    a3 = fmaf(se[rq * 4 + 3][k], w, a3);
  }
  float bj = bias[j];
  G[(long)(r0 + rq * 4 + 0) * H3z + j] = a0 + bj;
  G[(long)(r0 + rq * 4 + 1) * H3z + j] = a1 + bj;
  G[(long)(r0 + rq * 4 + 2) * H3z + j] = a2 + bj;
  G[(long)(r0 + rq * 4 + 3) * H3z + j] = a3 + bj;
}

// ---------------- fp32 -> bf16 convert ----------------
__global__ void k_f2bf(const float* __restrict__ in, unsigned short* __restrict__ out, long n4) {
  long i = (long)blockIdx.x * blockDim.x + threadIdx.x;
  long stride = (long)gridDim.x * blockDim.x;
  for (; i < n4; i += stride) {
    float4 v = ((const float4*)in)[i];
    ushort4 o;
    o.x = f2bf(v.x); o.y = f2bf(v.y); o.z = f2bf(v.z); o.w = f2bf(v.w);
    ((ushort4*)out)[i] = o;
  }
}

// ---------------- GRU cell phase ----------------
struct GruArgs {
  const float* gi_pre;   // [32][1536] (incl. bih) or nullptr
  const float* xvec;     // [32][512] or nullptr
  const float* wihT;     // [512][1536] if xvec
  const float* bih;      // [1536] or nullptr
  const float* hold;     // [32][512]
  const float* whhT;     // [512][1536]
  const float* bhh;      // [1536]
  float* hnew;           // [32][512]
  float* fout;           // optional: [b*fstride + j]
  long fstride;
  unsigned short* bfout; // optional bf16: [b*1024 + j]
  int active;
};

__device__ __forceinline__ void gru_block(int blk, const GruArgs& A, float* sh, float* sx) {
  int jg = blk >> 3, bg = blk & 7;
  int tid = threadIdx.x;
  int jj = tid & 63, bq = tid >> 6;
  int b = bg * 4 + bq;
  int j = jg * 64 + jj;
  for (int c = tid; c < 4 * Hz; c += 256) {
    int rl = c >> 9, k = c & 511;
    sh[c] = A.hold[(long)(bg * 4 + rl) * Hz + k];
    if (A.xvec) sx[c] = A.xvec[(long)(bg * 4 + rl) * Hz + k];
  }
  __syncthreads();
  const float* hb = sh + bq * Hz;
  const float* xb = sx + bq * Hz;
  float ar = 0.f, az = 0.f, an = 0.f, xr = 0.f, xz = 0.f, xn = 0.f;
  if (A.xvec) {
#pragma unroll 4
    for (int k = 0; k < Hz; ++k) {
      float hk = hb[k], xk = xb[k];
      const float* w = A.whhT + (long)k * H3z + j;
      const float* w2 = A.wihT + (long)k * H3z + j;
      ar = fmaf(hk, w[0], ar);   az = fmaf(hk, w[512], az);   an = fmaf(hk, w[1024], an);
      xr = fmaf(xk, w2[0], xr);  xz = fmaf(xk, w2[512], xz);  xn = fmaf(xk, w2[1024], xn);
    }
  } else {
#pragma unroll 4
    for (int k = 0; k < Hz; ++k) {
      float hk = hb[k];
      const float* w = A.whhT + (long)k * H3z + j;
      ar = fmaf(hk, w[0], ar);   az = fmaf(hk, w[512], az);   an = fmaf(hk, w[1024], an);
    }
  }
  float gir = 0.f, giz = 0.f, gin = 0.f;
  if (A.gi_pre) {
    gir = A.gi_pre[(long)b * H3z + j];
    giz = A.gi_pre[(long)b * H3z + 512 + j];
    gin = A.gi_pre[(long)b * H3z + 1024 + j];
  }
  if (A.xvec) { gir += xr; giz += xz; gin += xn; }
  if (A.bih)  { gir += A.bih[j]; giz += A.bih[512 + j]; gin += A.bih[1024 + j]; }
  float ghr = ar + A.bhh[j], ghz = az + A.bhh[512 + j], ghn = an + A.bhh[1024 + j];
  float r = 1.f / (1.f + __expf(-(gir + ghr)));
  float z = 1.f / (1.f + __expf(-(giz + ghz)));
  float n = tanhf(gin + r * ghn);
  float hv = hb[j];
  float hp = (1.f - z) * n + z * hv;
  A.hnew[(long)b * Hz + j] = hp;
  if (A.fout)  A.fout[(long)b * A.fstride + j] = hp;
  if (A.bfout) A.bfout[(long)b * 1024 + j] = f2bf(hp);
}

__global__ __launch_bounds__(256) void k_gru_pair(GruArgs a0, GruArgs a1) {
  __shared__ float sh[4 * Hz];
  __shared__ float sx[4 * Hz];
  if (blockIdx.x < 64) { if (a0.active) gru_block(blockIdx.x, a0, sh, sx); }
  else                 { if (a1.active) gru_block(blockIdx.x - 64, a1, sh, sx); }
}

__global__ __launch_bounds__(256) void k_gru_one(GruArgs a0) {
  __shared__ float sh[4 * Hz];
  __shared__ float sx[4 * Hz];
  gru_block(blockIdx.x, a0, sh, sx);
}

// ---------------- ke[b,s,h] = sum_k attn_w[h,k] * enc_out[b,s,k] ----------------
__global__ __launch_bounds__(256)
void k_ke(const float* __restrict__ enc_out, const float* __restrict__ attn_wT,
          float* __restrict__ ke) {
  __shared__ float se[8][Hz];
  int r0 = blockIdx.x * 8;
  int tid = threadIdx.x;
  for (int c = tid; c < 8 * Hz; c += 256) se[c >> 9][c & 511] = enc_out[(long)r0 * Hz + c];
  __syncthreads();
  int jj = tid & 63, rq = tid >> 6;  // rq handles rows rq*2, rq*2+1
  float acc0[8] = {0, 0, 0, 0, 0, 0, 0, 0};
  float acc1[8] = {0, 0, 0, 0, 0, 0, 0, 0};
#pragma unroll 2
  for (int k = 0; k < Hz; ++k) {
    float e0 = se[rq * 2][k], e1 = se[rq * 2 + 1][k];
#pragma unroll
    for (int jc = 0; jc < 8; ++jc) {
      float w = attn_wT[(long)k * Hz + jc * 64 + jj];
      acc0[jc] = fmaf(e0, w, acc0[jc]);
      acc1[jc] = fmaf(e1, w, acc1[jc]);
    }
  }
#pragma unroll
  for (int jc = 0; jc < 8; ++jc) {
    ke[(long)(r0 + rq * 2) * Hz + jc * 64 + jj] = acc0[jc];
    ke[(long)(r0 + rq * 2 + 1) * Hz + jc * 64 + jj] = acc1[jc];
  }
}

// ---------------- attention: scores -> softmax -> ctx ----------------
__global__ __launch_bounds__(256)
void k_attn(const float* __restrict__ d1, const float* __restrict__ ke,
            const float* __restrict__ enc_out, const int* __restrict__ src,
            float* __restrict__ ctxn, unsigned short* __restrict__ bfctx) {
  __shared__ float sd[Hz];
  __shared__ float sc[Sz];
  int b = blockIdx.x, tid = threadIdx.x;
  sd[tid] = d1[b * Hz + tid];
  sd[tid + 256] = d1[b * Hz + tid + 256];
  __syncthreads();
  int s = tid >> 2, q = tid & 3;
  const float4* kp = (const float4*)(ke + ((long)b * Sz + s) * Hz + q * 128);
  const float4* dp = (const float4*)(sd + q * 128);
  float p = 0.f;
#pragma unroll 8
  for (int i = 0; i < 32; ++i) {
    float4 v = kp[i];
    float4 d = dp[i];
    p += v.x * d.x + v.y * d.y + v.z * d.z + v.w * d.w;
  }
  p += __shfl_xor(p, 1);
  p += __shfl_xor(p, 2);
  if (q == 0) sc[s] = (src[b * 64 + s] == 0) ? -1e9f : p;
  __syncthreads();
  if (tid < 64) {
    float v = sc[tid];
    float m = v;
    for (int o = 32; o; o >>= 1) m = fmaxf(m, __shfl_xor(m, o));
    float e = __expf(v - m);
    float sum = e;
    for (int o = 32; o; o >>= 1) sum += __shfl_xor(sum, o);
    sc[tid] = e / sum;
  }
  __syncthreads();
  float a0 = 0.f, a1 = 0.f;
#pragma unroll 4
  for (int s2 = 0; s2 < Sz; ++s2) {
    float w = sc[s2];
    const float* er = enc_out + ((long)b * Sz + s2) * Hz;
    a0 = fmaf(w, er[tid], a0);
    a1 = fmaf(w, er[tid + 256], a1);
  }
  ctxn[b * Hz + tid] = a0;
  ctxn[b * Hz + tid + 256] = a1;
  bfctx[b * 1024 + tid] = f2bf(a0);
  bfctx[b * 1024 + tid + 256] = f2bf(a1);
}

// ---------------- final bf16 MFMA GEMM: out[b,t,:] = [d1|ctx] @ out_w^T + out_b --
// A: [2048][1024] bf16 (rows t*32+b, padded), B: out_w bf16 [32000][1024]
__global__ __launch_bounds__(256)
void k_out_gemm(const unsigned short* __restrict__ A, const unsigned short* __restrict__ Bw,
                const float* __restrict__ bias, float* __restrict__ out) {
  __shared__ __align__(16) char lds[32768];  // A tile 16KB | B tile 16KB
  int bid = blockIdx.x;
  int bm = bid & 15, bn = bid >> 4;  // 16 x 250
  long m0 = (long)bm * 128, n0 = (long)bn * 128;
  int tid = threadIdx.x, lane = tid & 63, wid = tid >> 6;
  int wm = wid >> 1, wn = wid & 1;  // 2x2 waves, 64x64 each
  floatx4 acc[4][4];
#pragma unroll
  for (int i = 0; i < 4; i++)
#pragma unroll
    for (int jx = 0; jx < 4; jx++) acc[i][jx] = (floatx4){0.f, 0.f, 0.f, 0.f};

  int rl = lane >> 3;                        // row within 8-row chunk
  int kb = (((lane & 7) ^ rl) << 4);         // swizzled source k-byte within 128B slice

  for (int kt = 0; kt < 16; ++kt) {
    long kbyte0 = (long)kt * 128;
#pragma unroll
    for (int q = 0; q < 4; ++q) {
      int c = wid * 4 + q;                   // chunk 0..15 (8 rows each)
      int row = c * 8 + rl;
      const char* ga = (const char*)A + (m0 + row) * 2048 + kbyte0 + kb;
      const char* gb = (const char*)Bw + (n0 + row) * 2048 + kbyte0 + kb;
      __builtin_amdgcn_global_load_lds(
          (const __attribute__((address_space(1))) void*)ga,
          (__attribute__((address_space(3))) void*)(lds + (c << 10)), 16, 0, 0);
      __builtin_amdgcn_global_load_lds(
          (const __attribute__((address_space(1))) void*)gb,
          (__attribute__((address_space(3))) void*)(lds + 16384 + (c << 10)), 16, 0, 0);
    }
    asm volatile("s_waitcnt vmcnt(0)" ::: "memory");
    __syncthreads();
#pragma unroll
    for (int kk = 0; kk < 2; ++kk) {
      shortx8 af[4], bf[4];
#pragma unroll
      for (int f = 0; f < 4; ++f) {
        int rowA = wm * 64 + f * 16 + (lane & 15);
        int cbA = (kk * 64 + ((lane >> 4) << 4)) ^ ((rowA & 7) << 4);
        af[f] = *(const shortx8*)(lds + rowA * 128 + cbA);
        int rowB = wn * 64 + f * 16 + (lane & 15);
        int cbB = (kk * 64 + ((lane >> 4) << 4)) ^ ((rowB & 7) << 4);
        bf[f] = *(const shortx8*)(lds + 16384 + rowB * 128 + cbB);
      }
#pragma unroll
      for (int mf = 0; mf < 4; ++mf)
#pragma unroll
        for (int nf = 0; nf < 4; ++nf)
          acc[mf][nf] = __builtin_amdgcn_mfma_f32_16x16x32_bf16(af[mf], bf[nf], acc[mf][nf], 0, 0, 0);
    }
    __syncthreads();
  }
  // epilogue: C row = (lane>>4)*4 + r, col = lane&15
#pragma unroll
  for (int mf = 0; mf < 4; ++mf) {
#pragma unroll
    for (int nf = 0; nf < 4; ++nf) {
      long gn = n0 + wn * 64 + nf * 16 + (lane & 15);
      float bb = bias[gn];
#pragma unroll
      for (int r = 0; r < 4; ++r) {
        long gm = m0 + wm * 64 + mf * 16 + ((lane >> 4) * 4) + r;
        if (gm < (long)Tdec * Bz) {
          long t = gm >> 5, b = gm & 31;
          out[(b * Tdec + t) * (long)Vz + gn] = acc[mf][nf][r] + bb;
        }
      }
    }
  }
}

extern "C" void kernel_launch(void* const* d_in, const int* in_sizes, int n_in,
                              void* d_out, int out_size, void* d_ws, size_t ws_size,
                              hipStream_t stream) {
  const int*   src      = (const int*)d_in[0];
  const int*   tgt      = (const int*)d_in[1];
  const float* enc_emb  = (const float*)d_in[2];
  const float* enc_wih0 = (const float*)d_in[3];
  const float* enc_whh0 = (const float*)d_in[4];
  const float* enc_bih0 = (const float*)d_in[5];
  const float* enc_bhh0 = (const float*)d_in[6];
  const float* enc_wih1 = (const float*)d_in[7];
  const float* enc_whh1 = (const float*)d_in[8];
  const float* enc_bih1 = (const float*)d_in[9];
  const float* enc_bhh1 = (const float*)d_in[10];
  const float* dec_emb  = (const float*)d_in[11];
  const float* dec_wih0 = (const float*)d_in[12];
  const float* dec_whh0 = (const float*)d_in[13];
  const float* dec_bih0 = (const float*)d_in[14];
  const float* dec_bhh0 = (const float*)d_in[15];
  const float* dec_wih1 = (const float*)d_in[16];
  const float* dec_whh1 = (const float*)d_in[17];
  const float* dec_bih1 = (const float*)d_in[18];
  const float* dec_bhh1 = (const float*)d_in[19];
  const float* attn_w   = (const float*)d_in[20];
  const float* out_w    = (const float*)d_in[21];
  const float* out_b    = (const float*)d_in[22];
  float* out = (float*)d_out;

  char* ws = (char*)d_ws;
  size_t off = 0;
  auto alloc = [&](size_t bytes) -> char* {
    char* p = ws + off;
    off += (bytes + 255) & ~(size_t)255;
    return p;
  };
  float* wtEncWih0  = (float*)alloc((size_t)Ez * H3z * 4);
  float* wtEncWhh0  = (float*)alloc((size_t)Hz * H3z * 4);
  float* wtEncWih1  = (float*)alloc((size_t)Hz * H3z * 4);
  float* wtEncWhh1  = (float*)alloc((size_t)Hz * H3z * 4);
  float* wtDecWih0E = (float*)alloc((size_t)Ez * H3z * 4);
  float* wtDecWih0C = (float*)alloc((size_t)Hz * H3z * 4);
  float* wtDecWhh0  = (float*)alloc((size_t)Hz * H3z * 4);
  float* wtDecWih1  = (float*)alloc((size_t)Hz * H3z * 4);
  float* wtDecWhh1  = (float*)alloc((size_t)Hz * H3z * 4);
  float* wtAttn     = (float*)alloc((size_t)Hz * Hz * 4);
  float* giEnc      = (float*)alloc((size_t)Sz * Bz * H3z * 4);
  float* giDec      = (float*)alloc((size_t)Tdec * Bz * H3z * 4);
  float* encOut     = (float*)alloc((size_t)Bz * Sz * Hz * 4);
  float* ke         = (float*)alloc((size_t)Bz * Sz * Hz * 4);
  float* h0buf      = (float*)alloc((size_t)2 * Bz * Hz * 4);
  float* h1buf      = (float*)alloc((size_t)2 * Bz * Hz * 4);
  float* d0buf      = (float*)alloc((size_t)2 * Bz * Hz * 4);
  float* d1buf      = (float*)alloc((size_t)2 * Bz * Hz * 4);
  float* ctxbuf     = (float*)alloc((size_t)2 * Bz * Hz * 4);
  unsigned short* d1ctxBf = (unsigned short*)alloc((size_t)2048 * 1024 * 2);
  unsigned short* outwBf  = (unsigned short*)alloc((size_t)Vz * 1024 * 2);
  if (off > ws_size) return;  // workspace too small -> loud absmax failure

  dim3 tb(256);
  // weight transposes
  k_transpose<<<dim3(Ez / 32, H3z / 32), tb, 0, stream>>>(enc_wih0, H3z, Ez, 0, wtEncWih0);
  k_transpose<<<dim3(Hz / 32, H3z / 32), tb, 0, stream>>>(enc_whh0, H3z, Hz, 0, wtEncWhh0);
  k_transpose<<<dim3(Hz / 32, H3z / 32), tb, 0, stream>>>(enc_wih1, H3z, Hz, 0, wtEncWih1);
  k_transpose<<<dim3(Hz / 32, H3z / 32), tb, 0, stream>>>(enc_whh1, H3z, Hz, 0, wtEncWhh1);
  k_transpose<<<dim3(Ez / 32, H3z / 32), tb, 0, stream>>>(dec_wih0, H3z, Ez + Hz, 0, wtDecWih0E);
  k_transpose<<<dim3(Hz / 32, H3z / 32), tb, 0, stream>>>(dec_wih0, H3z, Ez + Hz, Ez, wtDecWih0C);
  k_transpose<<<dim3(Hz / 32, H3z / 32), tb, 0, stream>>>(dec_whh0, H3z, Hz, 0, wtDecWhh0);
  k_transpose<<<dim3(Hz / 32, H3z / 32), tb, 0, stream>>>(dec_wih1, H3z, Hz, 0, wtDecWih1);
  k_transpose<<<dim3(Hz / 32, H3z / 32), tb, 0, stream>>>(dec_whh1, H3z, Hz, 0, wtDecWhh1);
  k_transpose<<<dim3(Hz / 32, Hz / 32), tb, 0, stream>>>(attn_w, Hz, Hz, 0, wtAttn);

  // state init
  hipMemsetAsync(h0buf, 0, (size_t)2 * Bz * Hz * 4, stream);
  hipMemsetAsync(h1buf, 0, (size_t)2 * Bz * Hz * 4, stream);
  hipMemsetAsync(ctxbuf, 0, (size_t)2 * Bz * Hz * 4, stream);
  hipMemsetAsync(d1ctxBf + (size_t)2016 * 1024, 0, (size_t)32 * 1024 * 2, stream);  // pad rows

  // precomputed input contributions + bf16 weight convert
  k_embed_gi<<<24 * 128, tb, 0, stream>>>(src, enc_emb, wtEncWih0, enc_bih0, giEnc);
  k_embed_gi<<<24 * 126, tb, 0, stream>>>(tgt, dec_emb, wtDecWih0E, dec_bih0, giDec);
  k_f2bf<<<2048, tb, 0, stream>>>(out_w, outwBf, (long)Vz * 1024 / 4);

  // encoder: layer1 pipelined one step behind layer0
  for (int i = 0; i < Sz + 1; ++i) {
    GruArgs a0 = {}; GruArgs a1 = {};
    if (i < Sz) {
      a0.gi_pre = giEnc + (long)i * Bz * H3z;
      a0.hold = h0buf + (size_t)(i & 1) * Bz * Hz;
      a0.whhT = wtEncWhh0; a0.bhh = enc_bhh0;
      a0.hnew = h0buf + (size_t)((i + 1) & 1) * Bz * Hz;
      a0.active = 1;
    }
    if (i >= 1) {
      int t = i - 1;
      a1.xvec = h0buf + (size_t)(i & 1) * Bz * Hz;  // h0[t] written last launch
      a1.wihT = wtEncWih1; a1.bih = enc_bih1;
      a1.hold = h1buf + (size_t)(t & 1) * Bz * Hz;
      a1.whhT = wtEncWhh1; a1.bhh = enc_bhh1;
      a1.hnew = h1buf + (size_t)((t + 1) & 1) * Bz * Hz;
      a1.fout = encOut + (long)t * Hz; a1.fstride = (long)Sz * Hz;
      a1.active = 1;
    }
    k_gru_pair<<<128, tb, 0, stream>>>(a0, a1);
  }

  // decoder init: d0 <- enc h0 final (slot 0), d1 <- enc h1 final (slot 0)
  hipMemcpyAsync(d0buf, h0buf, (size_t)Bz * Hz * 4, hipMemcpyDeviceToDevice, stream);
  hipMemcpyAsync(d1buf, h1buf, (size_t)Bz * Hz * 4, hipMemcpyDeviceToDevice, stream);

  // ke = enc_out @ attn_w^T (per (b,s) row)
  k_ke<<<256, tb, 0, stream>>>(encOut, wtAttn, ke);

  // decoder: 3 sequential phases per step
  for (int t = 0; t < Tdec; ++t) {
    int cs = t & 1, ns = (t + 1) & 1;
    GruArgs a = {};
    a.gi_pre = giDec + (long)t * Bz * H3z;
    a.xvec = ctxbuf + (size_t)cs * Bz * Hz;
    a.wihT = wtDecWih0C;               // bih already inside gi_pre
    a.hold = d0buf + (size_t)cs * Bz * Hz;
    a.whhT = wtDecWhh0; a.bhh = dec_bhh0;
    a.hnew = d0buf + (size_t)ns * Bz * Hz;
    a.active = 1;
    k_gru_one<<<64, tb, 0, stream>>>(a);

    GruArgs b = {};
    b.xvec = d0buf + (size_t)ns * Bz * Hz;
    b.wihT = wtDecWih1; b.bih = dec_bih1;
    b.hold = d1buf + (size_t)cs * Bz * Hz;
    b.whhT = wtDecWhh1; b.bhh = dec_bhh1;
    b.hnew = d1buf + (size_t)ns * Bz * Hz;
    b.bfout = d1ctxBf + (size_t)t * Bz * 1024;  // d1 half of GEMM A-row
    b.active = 1;
    k_gru_one<<<64, tb, 0, stream>>>(b);

    k_attn<<<Bz, tb, 0, stream>>>(d1buf + (size_t)ns * Bz * Hz, ke, encOut, src,
                                  ctxbuf + (size_t)ns * Bz * Hz,
                                  d1ctxBf + (size_t)t * Bz * 1024 + 512);
  }

  // batched output projection (bf16 MFMA)
  k_out_gemm<<<16 * 250, tb, 0, stream>>>(d1ctxBf, outwBf, out_b, out);
}